// Round 10
// baseline (30.050 us; speedup 1.0000x reference)
//
#include <hip/hip_runtime.h>
#include <cstdint>

#define IN_F 4096
#define OUT_F 11008
#define Q_OUT 5504
#define GROUP 128
#define BATCH 32

#define KBS 8            // k-splits (gridDim.y)
#define GPB 4            // quant groups per block
#define NCH 8            // 64-k chunks per block (K=512)
#define BN 128           // output cols per block (64 packed ints -> 256-B runs)
#define BST 18           // b_lds dword stride per n-row: 16 data + 2 pad

typedef int   i32x4 __attribute__((ext_vector_type(4)));
typedef float f32x4 __attribute__((ext_vector_type(4)));

// ---------------------------------------------------------------------------
// Prep kernel, two roles by blockIdx:
//  blocks 0..31: row m: maxabs -> delta[m]; quantize x to i8 in MFMA A-frag
//    order; per-group row sums Sx[g][m] (i32, exact).
//  blocks 32..117: out[m][n] = bias[n]  (16 floats/thread; gemm atomics add)
// ---------------------------------------------------------------------------
__global__ __launch_bounds__(256)
void prep_kernel(const float* __restrict__ x,
                 const float* __restrict__ bias,
                 uint4* __restrict__ xq,     // 8192 slots of 16 i8
                 int*   __restrict__ Sx,     // [32 g][32 m]
                 float* __restrict__ delta,  // [32]
                 float* __restrict__ out)
{
    const int t = threadIdx.x;
    if (blockIdx.x >= 32) {
        const int base = (blockIdx.x - 32) * 4096 + t * 16;
        #pragma unroll
        for (int i = 0; i < 4; ++i)
            *reinterpret_cast<float4*>(out + base + i * 4) =
                *reinterpret_cast<const float4*>(bias + ((base + i * 4) % OUT_F));
        return;
    }
    const int m = blockIdx.x;
    const float* xr = x + (size_t)m * IN_F + t * 16;  // thread owns k=16t..16t+15
    float4 v[4];
    #pragma unroll
    for (int i = 0; i < 4; ++i) v[i] = reinterpret_cast<const float4*>(xr)[i];

    float lm = 0.f;
    #pragma unroll
    for (int i = 0; i < 4; ++i) {
        lm = fmaxf(lm, fmaxf(fmaxf(fabsf(v[i].x), fabsf(v[i].y)),
                             fmaxf(fabsf(v[i].z), fabsf(v[i].w))));
    }
    #pragma unroll
    for (int d = 32; d; d >>= 1) lm = fmaxf(lm, __shfl_xor(lm, d));
    __shared__ float wred[4];
    if ((t & 63) == 0) wred[t >> 6] = lm;
    __syncthreads();
    const float mx  = fmaxf(fmaxf(wred[0], wred[1]), fmaxf(wred[2], wred[3]));
    const float inv = mx > 0.f ? 127.0f / mx : 0.f;

    int q[16];
    #pragma unroll
    for (int i = 0; i < 4; ++i) {
        q[i * 4 + 0] = __float2int_rn(v[i].x * inv);
        q[i * 4 + 1] = __float2int_rn(v[i].y * inv);
        q[i * 4 + 2] = __float2int_rn(v[i].z * inv);
        q[i * 4 + 3] = __float2int_rn(v[i].w * inv);
    }
    uint4 w;
    uint* wp = reinterpret_cast<uint*>(&w);
    #pragma unroll
    for (int i = 0; i < 4; ++i)
        wp[i] = (q[i*4] & 255) | ((q[i*4+1] & 255) << 8) |
                ((q[i*4+2] & 255) << 16) | ((q[i*4+3] & 255) << 24);
    // slot = S*128 + f*64 + kg*16 + (m&15);  S=t>>2, kg=t&3, f=m>>4
    xq[(t >> 2) * 128 + (m >> 4) * 64 + (t & 3) * 16 + (m & 15)] = w;

    int psum = 0;
    #pragma unroll
    for (int i = 0; i < 16; ++i) psum += q[i];
    #pragma unroll
    for (int d = 4; d; d >>= 1) psum += __shfl_down(psum, d, 8);
    if ((t & 7) == 0) Sx[(t >> 3) * 32 + m] = psum;   // g = t>>3
    if (t == 0) delta[m] = mx * (1.0f / 127.0f);
}

// ---------------------------------------------------------------------------
// GEMM: per block M=32, N=128, K=512 (4 groups). 8 waves, each 16 cols.
// == r5 kernel with ONE structural change: BN 64->128 @ 512 threads, so each
//    B-load's 16-lane group covers a 256-B contiguous run of a qw row (2x r5)
//    — clean test of the DRAM short-burst theory. Per-wave inner loop, k-split
//    count, atomic writers/address all IDENTICAL to r5. ==
// B: thread loads 4 rows x dwordx2 (c2 = int-pair 0..31, rq = row-quad 0..15);
//    vertical byte pack + nibble split -> 4 b32 LDS writes, kd XOR-swizzled
//    (kd ^= (c2&3)<<2) to keep banking ~4-way; read side kg ^= (cl>>2).
// A: i8 frags, 16 KB staged once via global_load_lds; 2 x ds_read_b128/chunk.
// Per group (2 chunks): acc_i32 -> accf += s*(D - z*Sx).
// Epilogue: out += delta_m * accf via unsafeAtomicAdd (out = bias by prep).
// ---------------------------------------------------------------------------
__global__ __launch_bounds__(512)
void int4_gemm_i8(const uint4* __restrict__ xq,
                  const int*   __restrict__ qw,
                  const float* __restrict__ scales,
                  const int*   __restrict__ qz,
                  const int*   __restrict__ Sx,
                  const float* __restrict__ delta,
                  float*       __restrict__ out)
{
    const int tid  = threadIdx.x;
    const int lane = tid & 63;
    const int wid  = tid >> 6;            // 0..7
    const int nb   = blockIdx.x;          // 0..85
    const int kb   = blockIdx.y;          // 0..7
    const int g0   = kb * GPB;
    const int k0b  = g0 * GROUP;

    __shared__ uint4 a_lds[1024];         // 16 KB, read-only after prologue
    __shared__ int   b_lds[2][128 * BST]; // 2 x 9 KB

    const int cl  = lane & 15;
    const int kg  = lane >> 4;
    const int n   = nb * BN + wid * 16 + cl;
    const int shn = (cl & 1) * 4;

    // ---- A stage: this kb's 1024 contiguous uint4 slots -> LDS, linear ----
    #pragma unroll
    for (int r = 0; r < 2; ++r) {
        const uint4* gp = xq + (size_t)kb * 1024 + r * 512 + tid;
        __builtin_amdgcn_global_load_lds(
            (const __attribute__((address_space(1))) uint32_t*)gp,
            (__attribute__((address_space(3))) uint32_t*)&a_lds[r * 512 + wid * 64],
            16, 0, 0);
    }

    // per-group constants
    int   zv[GPB];
    float sv[GPB];
    #pragma unroll
    for (int g = 0; g < GPB; ++g) {
        sv[g] = scales[(size_t)(g0 + g) * OUT_F + n];
        zv[g] = (qz[(size_t)(g0 + g) * Q_OUT + (n >> 1)] >> shn) & 15;
    }

    // B staging: c2 = int-pair column 0..31, rq = row-quad 0..15
    const int c2   = tid & 31;
    const int rq   = tid >> 5;
    const int kd_s = rq ^ ((c2 & 3) << 2);   // XOR-swizzled kd (bijective /4-blk)

    uint2 d[2][4];                        // [set][row]
    i32x4 acc_i[2] = {};
    f32x4 accf[2]  = {};
    int4  sx0v = {}, sx1v = {};

    auto LOADB = [&](int c, int set) {
        const int kr = k0b + c * 64 + 4 * rq;
        #pragma unroll
        for (int i = 0; i < 4; ++i)
            d[set][i] = *reinterpret_cast<const uint2*>(
                qw + (size_t)(kr + i) * Q_OUT + nb * 64 + 2 * c2);
    };
    auto WLDS = [&](int buf, int set) {
        #pragma unroll
        for (int j = 0; j < 2; ++j) {
            // vertical pack: byte of rows 4rq..4rq+3 for packed col 2c2+j
            uint b0 = (j ? d[set][0].y : d[set][0].x) & 255u;
            uint b1 = (j ? d[set][1].y : d[set][1].x) & 255u;
            uint b2 = (j ? d[set][2].y : d[set][2].x) & 255u;
            uint b3 = (j ? d[set][3].y : d[set][3].x) & 255u;
            uint p  = b0 | (b1 << 8) | (b2 << 16) | (b3 << 24);
            const int nloc = 4 * c2 + 2 * j;   // (nloc>>2) == c2 for both rows
            b_lds[buf][(nloc + 0) * BST + kd_s] = (int)(p & 0x0F0F0F0Fu);
            b_lds[buf][(nloc + 1) * BST + kd_s] = (int)((p >> 4) & 0x0F0F0F0Fu);
        }
    };

    LOADB(0, 0);
    LOADB(1, 1);
    WLDS(0, 0);
    asm volatile("s_waitcnt vmcnt(0) lgkmcnt(0)" ::: "memory");
    __builtin_amdgcn_s_barrier();
    asm volatile("" ::: "memory");

    const int kgs = kg ^ (cl >> 2);       // read-side swizzle key
    #pragma unroll
    for (int c = 0; c < NCH; ++c) {
        const int cur = c & 1;
        const int gl  = c >> 1;
        // d[cur] was flushed to LDS by WLDS at end of iter c-1 (r5 discipline)
        if (c + 2 < NCH) LOADB(c + 2, cur);
        if ((c & 1) == 0) {   // group start: fetch Sx rows (L2-hot)
            sx0v = *reinterpret_cast<const int4*>(Sx + (g0 + gl) * 32 + kg * 4);
            sx1v = *reinterpret_cast<const int4*>(Sx + (g0 + gl) * 32 + 16 + kg * 4);
        }

        // B fragment: n-row (nibble-extracted i8), swizzled dword quad
        const int* bp = &b_lds[cur][(wid * 16 + cl) * BST + 4 * kgs];
        int2 qa = *reinterpret_cast<const int2*>(bp);
        int2 qb = *reinterpret_cast<const int2*>(bp + 2);
        i32x4 bv; bv[0] = qa.x; bv[1] = qa.y; bv[2] = qb.x; bv[3] = qb.y;

        uint4 a0 = a_lds[(c * 2 + 0) * 64 + lane];
        uint4 a1 = a_lds[(c * 2 + 1) * 64 + lane];
        acc_i[0] = __builtin_amdgcn_mfma_i32_16x16x64_i8(
            __builtin_bit_cast(i32x4, a0), bv, acc_i[0], 0, 0, 0);
        acc_i[1] = __builtin_amdgcn_mfma_i32_16x16x64_i8(
            __builtin_bit_cast(i32x4, a1), bv, acc_i[1], 0, 0, 0);

        if (c & 1) {          // group end: integer zero-point fixup, scale
            const int   zz = zv[gl];
            const float ss = sv[gl];
            int sxa[8] = { sx0v.x, sx0v.y, sx0v.z, sx0v.w,
                           sx1v.x, sx1v.y, sx1v.z, sx1v.w };
            #pragma unroll
            for (int f = 0; f < 2; ++f)
                #pragma unroll
                for (int r = 0; r < 4; ++r) {
                    int tt = acc_i[f][r] - zz * sxa[f * 4 + r];
                    accf[f][r] = fmaf(ss, (float)tt, accf[f][r]);
                }
            acc_i[0] = i32x4{0, 0, 0, 0};
            acc_i[1] = i32x4{0, 0, 0, 0};
        }

        if (c + 1 < NCH) {
            WLDS(cur ^ 1, cur ^ 1);
            asm volatile("s_waitcnt lgkmcnt(0)" ::: "memory");
            __builtin_amdgcn_s_barrier();
            asm volatile("" ::: "memory");
        }
    }

    // epilogue: C/D layout col=lane&15, row=(lane>>4)*4+reg; out += delta_m*accf
    float4 dl0 = *reinterpret_cast<const float4*>(delta + kg * 4);
    float4 dl1 = *reinterpret_cast<const float4*>(delta + 16 + kg * 4);
    const float dla[8] = { dl0.x, dl0.y, dl0.z, dl0.w, dl1.x, dl1.y, dl1.z, dl1.w };
    #pragma unroll
    for (int f = 0; f < 2; ++f)
        #pragma unroll
        for (int r = 0; r < 4; ++r) {
            const int m = f * 16 + kg * 4 + r;
            unsafeAtomicAdd(out + (size_t)m * OUT_F + n, dla[f * 4 + r] * accf[f][r]);
        }
}

extern "C" void kernel_launch(void* const* d_in, const int* in_sizes, int n_in,
                              void* d_out, int out_size, void* d_ws, size_t ws_size,
                              hipStream_t stream)
{
    const float* inp    = (const float*)d_in[0];
    const int*   qw     = (const int*)d_in[1];
    const float* scales = (const float*)d_in[2];
    const int*   qz     = (const int*)d_in[3];
    const float* bias   = (const float*)d_in[4];
    float*       out    = (float*)d_out;

    uint4* xq    = (uint4*)d_ws;                          // 128 KB
    int*   Sx    = (int*)((char*)d_ws + 131072);          // 4 KB
    float* delta = (float*)((char*)d_ws + 131072 + 4096); // 128 B

    // blocks 0..31: quantize rows + Sx + delta; blocks 32..117: out = bias
    prep_kernel<<<118, 256, 0, stream>>>(inp, bias, xq, Sx, delta, out);

    int4_gemm_i8<<<dim3(OUT_F / BN, KBS), 512, 0, stream>>>(
        xq, qw, scales, qz, Sx, delta, out);
}